// Round 2
// baseline (809.728 us; speedup 1.0000x reference)
//
#include <hip/hip_runtime.h>

#define XY 65160     // 360*181
#define NI 96
#define NO 96
#define NK 8
#define NT2 510      // ceil(XY/128); each block-tile covers 128 xy (32 per wave-pair)

typedef __attribute__((ext_vector_type(8))) short short8;
typedef __attribute__((ext_vector_type(4))) float floatx4;

union FragU { short8 v; unsigned u[4]; };

// hardware packed f32x2 -> bf16x2 (RNE), lo = first operand
static __device__ __forceinline__ unsigned cvt_pk(float lo, float hi) {
    unsigned r;
    asm("v_cvt_pk_bf16_f32 %0, %1, %2" : "=v"(r) : "v"(lo), "v"(hi));
    return r;
}

__global__ __launch_bounds__(512, 4) void cmult_kernel(
    const float* __restrict__ inp, const float* __restrict__ weight,
    const float* __restrict__ bias, float* __restrict__ out)
{
    // PLAIN packed bf16 (wr,wi) pairs in MFMA A-fragment order: 36 KB
    __shared__ unsigned wlds[36 * 64 * 4];
    __shared__ float2 blds[NO];              // bias staged once: 768 B

    const int tid  = threadIdx.x;
    const int lane = tid & 63;
    const int wave = tid >> 6;
    const int h    = wave & 1;       // o-half: 0 -> m 0..2, 1 -> m 3..5
    const int g    = wave >> 1;      // xy-group within 128-xy tile
    const int k    = blockIdx.y;
    const int l15  = lane & 15;
    const int quad = lane >> 4;

    const float* wk   = weight + (size_t)k * NI * NO * 2;
    const float* inpk = inp    + (size_t)k * NI * XY * 2;

    // ---- stage weight (fp32 -> packed bf16 pair, PLAIN) into A-fragment layout ----
    // fragment (s,m): lane holds o = 16m + (lane&15), kk = 32s + (lane>>4)*8 + j
    for (int idx = tid; idx < NI * NO; idx += 512) {
        int i = idx / NO;
        int o = idx - i * NO;
        float2 w = *reinterpret_cast<const float2*>(wk + (size_t)idx * 2);
        int s = i >> 4, q = (i >> 2) & 3, t = i & 3;
        int m = o >> 4, c = o & 15;
        wlds[((s * 6 + m) * 64 + (q * 16 + c)) * 4 + t] = cvt_pk(w.x, w.y);
    }
    if (tid < NO) {
        blds[tid] = *reinterpret_cast<const float2*>(bias + ((size_t)k * NO + tid) * 2);
    }
    __syncthreads();

    // ---- grid-stride loop: 128-xy tiles; wave owns 32 xy x 48 o ----
    for (int tidx = blockIdx.x; tidx < NT2; tidx += gridDim.x) {
        int x0  = tidx * 128 + g * 32 + 2 * l15;      // even; lane owns (x0, x0+1)
        int x0c = x0 <= XY - 2 ? x0 : XY - 2;         // clamp loads (stays even/aligned)

        floatx4 accRA[3], accIA[3], accRB[3], accIB[3];
        #pragma unroll
        for (int m = 0; m < 3; ++m) {
            accRA[m] = (floatx4){0.f,0.f,0.f,0.f}; accIA[m] = (floatx4){0.f,0.f,0.f,0.f};
            accRB[m] = (floatx4){0.f,0.f,0.f,0.f}; accIB[m] = (floatx4){0.f,0.f,0.f,0.f};
        }

        #pragma unroll
        for (int s = 0; s < 6; ++s) {
            // B variants: bN = (ar,-ai) -> real chain; bS = (ai,ar) -> imag chain
            FragU bNA, bSA, bNB, bSB;
            #pragma unroll
            for (int t = 0; t < 4; ++t) {
                int i = 16 * s + 4 * quad + t;
                float4 a = *reinterpret_cast<const float4*>(inpk + ((size_t)i * XY + x0c) * 2);
                unsigned pA = cvt_pk(a.x, a.y);            // (ar, ai) of xy = x0
                unsigned pB = cvt_pk(a.z, a.w);            // (ar, ai) of xy = x0+1
                bNA.u[t] = pA ^ 0x80000000u;               // (ar, -ai)
                bSA.u[t] = (pA >> 16) | (pA << 16);        // (ai,  ar)
                bNB.u[t] = pB ^ 0x80000000u;
                bSB.u[t] = (pB >> 16) | (pB << 16);
            }
            #pragma unroll
            for (int mm = 0; mm < 3; ++mm) {
                int m = 3 * h + mm;
                FragU wf;
                uint4 wp = *(reinterpret_cast<const uint4*>(wlds) + (s * 6 + m) * 64 + lane);
                wf.u[0] = wp.x; wf.u[1] = wp.y; wf.u[2] = wp.z; wf.u[3] = wp.w;
                // one plain weight fragment feeds 4 MFMAs (2 chains x 2 xy-fragments)
                accRA[mm] = __builtin_amdgcn_mfma_f32_16x16x32_bf16(wf.v, bNA.v, accRA[mm], 0, 0, 0);
                accIA[mm] = __builtin_amdgcn_mfma_f32_16x16x32_bf16(wf.v, bSA.v, accIA[mm], 0, 0, 0);
                accRB[mm] = __builtin_amdgcn_mfma_f32_16x16x32_bf16(wf.v, bNB.v, accRB[mm], 0, 0, 0);
                accIB[mm] = __builtin_amdgcn_mfma_f32_16x16x32_bf16(wf.v, bSB.v, accIB[mm], 0, 0, 0);
            }
        }

        // ---- epilogue: fuse even/odd xy into one float4 store (16B/lane) ----
        if (x0 < XY) {   // XY even -> x0 and x0+1 both valid together
            #pragma unroll
            for (int mm = 0; mm < 3; ++mm) {
                #pragma unroll
                for (int r = 0; r < 4; ++r) {
                    int o = 16 * (3 * h + mm) + 4 * quad + r;
                    float2 b = blds[o];
                    float4 ov;
                    ov.x = accRA[mm][r] + b.x;
                    ov.y = accIA[mm][r] + b.y;
                    ov.z = accRB[mm][r] + b.x;
                    ov.w = accIB[mm][r] + b.y;
                    *reinterpret_cast<float4*>(out + ((size_t)(k * NO + o) * XY + x0) * 2) = ov;
                }
            }
        }
    }
}

extern "C" void kernel_launch(void* const* d_in, const int* in_sizes, int n_in,
                              void* d_out, int out_size, void* d_ws, size_t ws_size,
                              hipStream_t stream)
{
    const float* inp    = (const float*)d_in[0];
    const float* weight = (const float*)d_in[1];
    const float* bias   = (const float*)d_in[2];
    float* out = (float*)d_out;

    dim3 grid(128, NK), block(512);
    hipLaunchKernelGGL(cmult_kernel, grid, block, 0, stream, inp, weight, bias, out);
}

// Round 4
// 796.947 us; speedup vs baseline: 1.0160x; 1.0160x over previous
//
#include <hip/hip_runtime.h>

#define XY 65160     // 360*181
#define NI 96
#define NO 96
#define NK 8
#define NT 510       // ceil(XY/128); each block-tile covers 128 xy (16 per wave)

typedef __attribute__((ext_vector_type(8))) short short8;
typedef __attribute__((ext_vector_type(4))) float floatx4;

union FragU { short8 v; unsigned u[4]; };

// hardware packed f32x2 -> bf16x2 (RNE), lo = first operand
static __device__ __forceinline__ unsigned cvt_pk(float lo, float hi) {
    unsigned r;
    asm("v_cvt_pk_bf16_f32 %0, %1, %2" : "=v"(r) : "v"(lo), "v"(hi));
    return r;
}

__global__ __launch_bounds__(512, 4) void cmult_kernel(
    const float* __restrict__ inp, const float* __restrict__ weight,
    const float* __restrict__ bias, float* __restrict__ out)
{
    // PLAIN packed bf16 (wr,wi) pairs in MFMA A-fragment order: 36 KB
    __shared__ unsigned wlds[36 * 64 * 4];
    __shared__ float2 blds[NO];              // bias staged once: 768 B

    const int tid  = threadIdx.x;
    const int lane = tid & 63;
    const int wave = tid >> 6;       // 8 waves, each owns 16 distinct xy
    const int k    = blockIdx.y;
    const int l15  = lane & 15;
    const int quad = lane >> 4;

    const float* wk   = weight + (size_t)k * NI * NO * 2;
    const float* inpk = inp    + (size_t)k * NI * XY * 2;

    // ---- stage weight (fp32 -> packed bf16 pair, PLAIN) into A-fragment layout ----
    // fragment (s,m): lane holds o = 16m + (lane&15), kk = 32s + (lane>>4)*8 + j
    for (int idx = tid; idx < NI * NO; idx += 512) {
        int i = idx / NO;
        int o = idx - i * NO;
        float2 w = *reinterpret_cast<const float2*>(wk + (size_t)idx * 2);
        int s = i >> 4, q = (i >> 2) & 3, t = i & 3;
        int m = o >> 4, c = o & 15;
        wlds[((s * 6 + m) * 64 + (q * 16 + c)) * 4 + t] = cvt_pk(w.x, w.y);
    }
    if (tid < NO) {
        blds[tid] = *reinterpret_cast<const float2*>(bias + ((size_t)k * NO + tid) * 2);
    }
    __syncthreads();

    // ---- grid-stride loop: 128-xy block tiles; wave owns 16 xy x 96 o ----
    for (int tidx = blockIdx.x; tidx < NT; tidx += gridDim.x) {
        int xy  = tidx * 128 + wave * 16 + l15;
        int xyc = xy < XY ? xy : XY - 1;          // clamp loads; stores predicated

        floatx4 accR[6], accI[6];
        #pragma unroll
        for (int m = 0; m < 6; ++m) {
            accR[m] = (floatx4){0.f,0.f,0.f,0.f};
            accI[m] = (floatx4){0.f,0.f,0.f,0.f};
        }

        #pragma unroll
        for (int s = 0; s < 6; ++s) {
            // B variants: bN = (ar,-ai) -> real chain; bS = (ai,ar) -> imag chain
            FragU bN, bS;
            #pragma unroll
            for (int t = 0; t < 4; ++t) {
                int i = 16 * s + 4 * quad + t;
                float2 a = *reinterpret_cast<const float2*>(inpk + ((size_t)i * XY + xyc) * 2);
                unsigned p = cvt_pk(a.x, a.y);            // (ar, ai)
                bN.u[t] = p ^ 0x80000000u;                // (ar, -ai)
                bS.u[t] = (p >> 16) | (p << 16);          // (ai,  ar)
            }
            #pragma unroll
            for (int m = 0; m < 6; ++m) {
                FragU wf;
                uint4 wp = *(reinterpret_cast<const uint4*>(wlds) + (s * 6 + m) * 64 + lane);
                wf.u[0] = wp.x; wf.u[1] = wp.y; wf.u[2] = wp.z; wf.u[3] = wp.w;
                // one plain weight fragment feeds both chains
                accR[m] = __builtin_amdgcn_mfma_f32_16x16x32_bf16(wf.v, bN.v, accR[m], 0, 0, 0);
                accI[m] = __builtin_amdgcn_mfma_f32_16x16x32_bf16(wf.v, bS.v, accI[m], 0, 0, 0);
            }
        }

        // ---- epilogue: D col = lane&15 (xy), row = quad*4 + r (o within 16-tile) ----
        if (xy < XY) {
            #pragma unroll
            for (int m = 0; m < 6; ++m) {
                #pragma unroll
                for (int r = 0; r < 4; ++r) {
                    int o = 16 * m + 4 * quad + r;
                    float2 b = blds[o];
                    float2 ov;
                    ov.x = accR[m][r] + b.x;
                    ov.y = accI[m][r] + b.y;
                    *reinterpret_cast<float2*>(out + ((size_t)(k * NO + o) * XY + xy) * 2) = ov;
                }
            }
        }
    }
}

extern "C" void kernel_launch(void* const* d_in, const int* in_sizes, int n_in,
                              void* d_out, int out_size, void* d_ws, size_t ws_size,
                              hipStream_t stream)
{
    const float* inp    = (const float*)d_in[0];
    const float* weight = (const float*)d_in[1];
    const float* bias   = (const float*)d_in[2];
    float* out = (float*)d_out;

    dim3 grid(128, NK), block(512);
    hipLaunchKernelGGL(cmult_kernel, grid, block, 0, stream, inp, weight, bias, out);
}